// Round 6
// baseline (1046.879 us; speedup 1.0000x reference)
//
#include <hip/hip_runtime.h>
#include <math.h>

// Sinkhorn-divergence margin loss, MI355X.
// Scaled domain: F = f/(eps*ln2), M = C/(eps*ln2); softmin via exp2/log2.
// Ragged prefix mask (len_b = length_anchor[b]) exploited with wave-uniform skips.
// waves_per_eu(4,4): pin VGPR budget to 128 -- launch_bounds(.,4) alone lets the
// scheduler target 8 waves/EU (budget 64) and spill (R4/R5: 139/64 MB scratch).
#define NL 256
#define ND 300
#define NC 5
#define NR 50

constexpr float SCf  = 577.07801635558534f;     // 1/(eps*ln2), eps=0.0025
constexpr float ELNf = 0.0017328679513998632f;  // eps*ln2
constexpr float BL2f = -5.6438561897747247f;    // log2(1/50)
constexpr float NEGB = -1.0e9f;
constexpr float MNEG = -3.0e38f;

// workspace layout (floats)
#define WS_XN   0        // 65536
#define WS_AL2  65536    // 65536
#define WS_YN   131072   // 256
#define WS_PA   131328   // 256
#define WS_QC   131584   // 16
#define WS_S    131600   // 1280

__device__ __forceinline__ float ex2(float x){ return __builtin_amdgcn_exp2f(x); }
__device__ __forceinline__ float lg2(float x){ return __builtin_amdgcn_logf(x); } // v_log_f32 = log2

// ---------------- k_pre: norms (scaled) + log2-weights ----------------
__global__ __launch_bounds__(256) void k_pre(const float* __restrict__ anchor,
                                             const float* __restrict__ weight,
                                             const float* __restrict__ t0,
                                             const int* __restrict__ lena,
                                             float* __restrict__ ws){
  const int blk=blockIdx.x, t=threadIdx.x;
  if(blk<256){
    const int len=lena[blk];
    const int lenS=(len+63)&~63;
    const int r=blk*256+t;
    if(t<lenS){
      const float4* row=(const float4*)(anchor+(size_t)r*ND);
      float s=0.f;
      #pragma unroll
      for(int k=0;k<75;k++){ float4 v=row[k];
        s=fmaf(v.x,v.x,fmaf(v.y,v.y,fmaf(v.z,v.z,fmaf(v.w,v.w,s)))); }
      ws[WS_XN+r]=0.5f*SCf*s;
    }
    const float w=weight[r];
    ws[WS_AL2+r]=(w>0.f)?log2f(w):NEGB;
  } else if(t<NC*NR){
    const float4* row=(const float4*)(t0+(size_t)t*ND);
    float s=0.f;
    #pragma unroll
    for(int k=0;k<75;k++){ float4 v=row[k];
      s=fmaf(v.x,v.x,fmaf(v.y,v.y,fmaf(v.z,v.z,fmaf(v.w,v.w,s)))); }
    ws[WS_YN+t]=0.5f*SCf*s;
  }
}

// ---------------- k_ab: blocks 0..255 -> p per b; 256..260 -> q per c ----
// mapping: i=t&255 (row), h=t>>8 (64-col chunk, wave-uniform) -> ragged skip
__global__ __launch_bounds__(1024)
__attribute__((amdgpu_waves_per_eu(4,4)))
void k_ab(const float* __restrict__ anchor,
          const float* __restrict__ weight,
          const float* __restrict__ t0,
          const int* __restrict__ lena,
          float* __restrict__ ws){
  __shared__ __align__(16) float4 xt4[1288];  // swizzled x-tile: xt4[5r + 2*(r>>6) + d4]
  __shared__ __align__(16) float xnL[256];
  __shared__ __align__(16) float HpP[4*68];   // H padded: col j -> (j>>6)*68+(j&63)
  __shared__ float PM[4*260];                 // per-(chunk,row) partial max
  __shared__ float PS[4*260];                 // per-(chunk,row) partial sum
  __shared__ float red[16];
  __shared__ __align__(16) float MyL[50*52];
  __shared__ float QL[64];
  __shared__ float padL[10240];               // occupancy limiter -> 1 block/CU (256 CUs busy)
  const int blk=blockIdx.x, t=threadIdx.x;
  if(blk<256){
    const int b=blk;
    const int len=lena[b];
    const int lenS=(len+63)&~63;
    if(len==-1) padL[t]=0.f;  // never true (len in 1..256): keeps padL allocated
    const int i=t&255, h=t>>8;
    const float* xb=anchor+(size_t)b*NL*ND;
    if(t<256) xnL[t]=ws[WS_XN+b*256+t];
    const float al2=ws[WS_AL2+b*256+i];
    if(t<256) HpP[(i>>6)*68+(i&63)]=al2;      // P=0 init (rows>=len stay -1e9)
    for(int e=t;e<1040;e+=1024){ PM[e]=MNEG; PS[e]=0.f; }
    const bool act=(i<len)&&(h*64<len);
    float Mr[64];
    #pragma unroll
    for(int j=0;j<64;j++) Mr[j]=0.f;
    // staging indices (reg-prefetch, rows < lenS only)
    const int r0=t/5, d40=t-r0*5;
    const bool st0=(r0<lenS);
    const int e1=t+1024;
    const int r1=e1/5, d41=e1-r1*5;
    const bool st1=(e1<1280)&&(r1<lenS);
    const float* g0p=xb+(size_t)r0*ND+d40*4;
    const float* g1p=xb+(size_t)r1*ND+d41*4;
    const int u0=5*r0+2*(r0>>6)+d40;
    const int u1=5*r1+2*(r1>>6)+d41;
    float4 pf0,pf1;
    if(st0) pf0=*(const float4*)(g0p);
    if(st1) pf1=*(const float4*)(g1p);
    const float4* xrowp=(const float4*)(xb+(size_t)i*ND);
    const int cb=322*h;  // 5*(64h)+2h
    #pragma unroll 1
    for(int tile=0;tile<15;tile++){
      __syncthreads();
      if(st0) xt4[u0]=pf0;
      if(st1) xt4[u1]=pf1;
      __syncthreads();
      if(tile<14){
        if(st0) pf0=*(const float4*)(g0p+(tile+1)*20);
        if(st1) pf1=*(const float4*)(g1p+(tile+1)*20);
      }
      if(act){
        const float4 xq0=xrowp[tile*5+0];
        const float4 xq1=xrowp[tile*5+1];
        const float4 xq2=xrowp[tile*5+2];
        const float4 xq3=xrowp[tile*5+3];
        const float4 xq4=xrowp[tile*5+4];
        #pragma unroll
        for(int jj=0;jj<64;jj++){
          const float4 y0=xt4[cb+5*jj+0];
          const float4 y1=xt4[cb+5*jj+1];
          const float4 y2=xt4[cb+5*jj+2];
          const float4 y3=xt4[cb+5*jj+3];
          const float4 y4=xt4[cb+5*jj+4];
          float acc=Mr[jj];
          acc=fmaf(xq0.x,y0.x,fmaf(xq0.y,y0.y,fmaf(xq0.z,y0.z,fmaf(xq0.w,y0.w,acc))));
          acc=fmaf(xq1.x,y1.x,fmaf(xq1.y,y1.y,fmaf(xq1.z,y1.z,fmaf(xq1.w,y1.w,acc))));
          acc=fmaf(xq2.x,y2.x,fmaf(xq2.y,y2.y,fmaf(xq2.z,y2.z,fmaf(xq2.w,y2.w,acc))));
          acc=fmaf(xq3.x,y3.x,fmaf(xq3.y,y3.y,fmaf(xq3.z,y3.z,fmaf(xq3.w,y3.w,acc))));
          acc=fmaf(xq4.x,y4.x,fmaf(xq4.y,y4.y,fmaf(xq4.z,y4.z,fmaf(xq4.w,y4.w,acc))));
          Mr[jj]=acc;
        }
      }
    }
    if(act){
      const float xni=xnL[i];
      #pragma unroll
      for(int jj=0;jj<64;jj++) Mr[jj]=xni+xnL[h*64+jj]-SCf*Mr[jj];
    }
    __syncthreads();
    float Pi=0.f;
    const float4* Hp4=(const float4*)HpP;
    #pragma unroll 1
    for(int it=0; it<51; ++it){
      if(act){
        float m0=MNEG,m1=MNEG,m2=MNEG,m3=MNEG;
        #pragma unroll
        for(int q=0;q<16;q++){
          const float4 hv=Hp4[h*17+q];
          m0=fmaxf(m0,hv.x-Mr[q*4+0]); m1=fmaxf(m1,hv.y-Mr[q*4+1]);
          m2=fmaxf(m2,hv.z-Mr[q*4+2]); m3=fmaxf(m3,hv.w-Mr[q*4+3]);
        }
        const float m=fmaxf(fmaxf(m0,m1),fmaxf(m2,m3));
        float s0=0.f,s1=0.f,s2=0.f,s3=0.f;
        #pragma unroll
        for(int q=0;q<16;q++){
          const float4 hv=Hp4[h*17+q];
          s0+=ex2(hv.x-Mr[q*4+0]-m); s1+=ex2(hv.y-Mr[q*4+1]-m);
          s2+=ex2(hv.z-Mr[q*4+2]-m); s3+=ex2(hv.w-Mr[q*4+3]-m);
        }
        PM[h*260+i]=m;
        PS[h*260+i]=(s0+s1)+(s2+s3);
      }
      __syncthreads();
      if(t<256 && i<len){
        const float p0=PM[i],p1=PM[260+i],p2=PM[520+i],p3=PM[780+i];
        const float mm=fmaxf(fmaxf(p0,p1),fmaxf(p2,p3));
        const float ssv=PS[i]*ex2(p0-mm)+PS[260+i]*ex2(p1-mm)
                       +PS[520+i]*ex2(p2-mm)+PS[780+i]*ex2(p3-mm);
        const float sm=-(mm+lg2(ssv));
        Pi=(it==0)?sm:0.5f*(Pi+sm);
        HpP[(i>>6)*68+(i&63)]=al2+Pi;
      }
      __syncthreads();
    }
    float cv=(t<256 && i<len)?(weight[b*256+i]*Pi):0.f;
    #pragma unroll
    for(int off=1;off<64;off<<=1) cv+=__shfl_xor(cv,off);
    if((t&63)==0) red[t>>6]=cv;
    __syncthreads();
    if(t==0){ float ss=0.f;
      #pragma unroll
      for(int k=0;k<16;k++) ss+=red[k];
      ws[WS_PA+b]=ELNf*ss; }
  } else {
    const int c=blk-256;
    const float* yc=t0+(size_t)c*NR*ND;
    #pragma unroll 1
    for(int rr=0;rr<3;rr++){
      const int o=t+1024*rr;
      if(o<2500){
        const int j=o/50, k=o-j*50;
        const float4* a4=(const float4*)(yc+(size_t)j*ND);
        const float4* b4=(const float4*)(yc+(size_t)k*ND);
        float s=0.f;
        #pragma unroll
        for(int d4=0;d4<75;d4++){ const float4 av=a4[d4],bv=b4[d4];
          s=fmaf(av.x,bv.x,fmaf(av.y,bv.y,fmaf(av.z,bv.z,fmaf(av.w,bv.w,s)))); }
        MyL[j*52+k]=ws[WS_YN+c*50+j]+ws[WS_YN+c*50+k]-SCf*s;
      }
    }
    if(t<64) QL[t]=0.f;
    __syncthreads();
    float My[50]; float Qj=0.f;
    if(t<50){
      #pragma unroll
      for(int k=0;k<50;k++) My[k]=MyL[t*52+k];
    }
    #pragma unroll 1
    for(int it=0; it<51; ++it){
      float sm=0.f;
      if(t<50){
        float m=MNEG; float sc[50];
        #pragma unroll
        for(int k=0;k<50;k++){ sc[k]=BL2f+QL[k]-My[k]; m=fmaxf(m,sc[k]); }
        float s=0.f;
        #pragma unroll
        for(int k=0;k<50;k++) s+=ex2(sc[k]-m);
        sm=-(m+lg2(s));
      }
      __syncthreads();
      if(t<50){ Qj=(it==0)?sm:0.5f*(Qj+sm); QL[t]=Qj; }
      __syncthreads();
    }
    float cv=(t<64)?((t<50)?Qj:0.f):0.f;
    if(t<64){
      #pragma unroll
      for(int off=1;off<64;off<<=1) cv+=__shfl_xor(cv,off);
    }
    if(t==0) ws[WS_QC+c]=ELNf*0.02f*cv;
  }
}

// ---------------- k_c: f,g iteration per (b,c); 512 thr, wave-role split ----------------
// waves 0..3: f-role, thread t owns row t, M-row in regs Reg[0..49]
// waves 4..7: g-role, lane=col(<50), wave covers row-chunk gc (64 rows) in regs Reg[0..63]
// Reg[] is a single union array; waves_per_eu(4,4) -> 128-VGPR budget, no spill.
__global__ __launch_bounds__(512)
__attribute__((amdgpu_waves_per_eu(4,4)))
void k_c(const float* __restrict__ anchor,
         const float* __restrict__ weight,
         const float* __restrict__ t0,
         const int* __restrict__ lena,
         float* __restrict__ ws){
  __shared__ __align__(16) float4 MTg[50*65]; // M^T: [col j][unit u=row/4], stride 65 units
  __shared__ __align__(16) float yt[1000];    // y-tile [50][20]
  __shared__ float ynL[52];
  __shared__ __align__(16) float AfP[8*40];   // al2+F padded: row r -> (r>>5)*40+(r&31), 16B-aligned
  __shared__ __align__(16) float GLb[52];     // BL2f + G
  __shared__ float PM[4*52];
  __shared__ float PS[4*52];
  __shared__ float red[5];
  const int blk=blockIdx.x, t=threadIdx.x;
  const int c=blk>>8, b=blk&255;
  const int len=lena[b];
  const int i=t>>1, h=t&1;          // GEMM mapping
  const bool rowAct=(i<len);
  const float* xb=anchor+(size_t)b*NL*ND;
  const float* yc=t0+(size_t)c*NR*ND;
  if(t<50) ynL[t]=ws[WS_YN+c*50+t];
  float Mr[25];
  #pragma unroll
  for(int k=0;k<25;k++) Mr[k]=0.f;
  // staging (reg-prefetch)
  const int sr=(t<250)?(t/5):0, sd=(t<250)?(t-(t/5)*5):0;
  const bool stg=(t<250);
  const float* gsp=yc+(size_t)sr*ND+sd*4;
  float4 pf;
  if(stg) pf=*(const float4*)gsp;
  #pragma unroll 1
  for(int tile=0;tile<15;tile++){
    __syncthreads();
    if(stg) *(float4*)&yt[sr*20+sd*4]=pf;
    __syncthreads();
    if(tile<14 && stg) pf=*(const float4*)(gsp+(tile+1)*20);
    if(rowAct){
      const float4* xrow=(const float4*)(xb+(size_t)i*ND+tile*20);
      const float4 xq0=xrow[0],xq1=xrow[1],xq2=xrow[2],xq3=xrow[3],xq4=xrow[4];
      #pragma unroll
      for(int k=0;k<25;k++){
        const int j=2*k+h;
        const float4 y0=*(const float4*)&yt[j*20+0];
        const float4 y1=*(const float4*)&yt[j*20+4];
        const float4 y2=*(const float4*)&yt[j*20+8];
        const float4 y3=*(const float4*)&yt[j*20+12];
        const float4 y4=*(const float4*)&yt[j*20+16];
        float acc=Mr[k];
        acc=fmaf(xq0.x,y0.x,fmaf(xq0.y,y0.y,fmaf(xq0.z,y0.z,fmaf(xq0.w,y0.w,acc))));
        acc=fmaf(xq1.x,y1.x,fmaf(xq1.y,y1.y,fmaf(xq1.z,y1.z,fmaf(xq1.w,y1.w,acc))));
        acc=fmaf(xq2.x,y2.x,fmaf(xq2.y,y2.y,fmaf(xq2.z,y2.z,fmaf(xq2.w,y2.w,acc))));
        acc=fmaf(xq3.x,y3.x,fmaf(xq3.y,y3.y,fmaf(xq3.z,y3.z,fmaf(xq3.w,y3.w,acc))));
        acc=fmaf(xq4.x,y4.x,fmaf(xq4.y,y4.y,fmaf(xq4.z,y4.z,fmaf(xq4.w,y4.w,acc))));
        Mr[k]=acc;
      }
    }
  }
  if(rowAct){
    const float xni=ws[WS_XN+b*256+i];
    #pragma unroll
    for(int k=0;k<25;k++) Mr[k]=xni+ynL[2*k+h]-SCf*Mr[k];
  }
  // transpose into MTg: row i -> unit i>>2, comp i&3 (rows>=len hold 0: finite)
  {
    const int QQ=i>>2, cc2=i&3;
    #pragma unroll
    for(int k=0;k<25;k++){
      ((float*)&MTg[(2*k+h)*65+QQ])[cc2]=Mr[k];
    }
  }
  __syncthreads();   // MTg ready
  // ---- roles ----
  const int w=t>>6, l=t&63;
  const bool isF=(w<4);
  const int gc=(w+2)&3;              // g-role row-chunk (SIMD-balancing rotation)
  const int col=l;
  const int colc=(col<50)?col:49;
  const bool fAct=isF&&(w*64<len);
  const bool gAct=(!isF)&&(gc*64<len)&&(col<50);
  float Reg[64];                     // union: f-role rows use [0..49], g-role uses [0..63]
  if(isF){
    const float* MT=(const float*)MTg;
    #pragma unroll
    for(int j=0;j<50;j++) Reg[j]=MT[j*260+t];
  } else {
    #pragma unroll
    for(int r4=0;r4<16;r4++){
      const float4 v=MTg[colc*65+gc*16+r4];
      Reg[4*r4+0]=v.x; Reg[4*r4+1]=v.y; Reg[4*r4+2]=v.z; Reg[4*r4+3]=v.w;
    }
  }
  const float al2v=(t<256)?ws[WS_AL2+b*256+t]:0.f;
  if(t<256) AfP[(t>>5)*40+(t&31)]=al2v;   // F=0 init (rows>=len: -1e9, exact-zero contrib)
  if(t<50) GLb[t]=BL2f;                   // G=0 init
  if(t<208){ PM[t]=MNEG; PS[t]=0.f; }
  __syncthreads();
  float Fi=0.f, Gj=0.f;
  #pragma unroll 1
  for(int it=0; it<51; ++it){
    float smf=0.f;
    if(fAct){
      float m0=MNEG,m1=MNEG,m2=MNEG,m3=MNEG;
      #pragma unroll
      for(int j4=0;j4<12;j4++){
        const float4 gv=*(const float4*)&GLb[j4*4];
        m0=fmaxf(m0,gv.x-Reg[j4*4+0]); m1=fmaxf(m1,gv.y-Reg[j4*4+1]);
        m2=fmaxf(m2,gv.z-Reg[j4*4+2]); m3=fmaxf(m3,gv.w-Reg[j4*4+3]);
      }
      m0=fmaxf(m0,GLb[48]-Reg[48]); m1=fmaxf(m1,GLb[49]-Reg[49]);
      const float mf=fmaxf(fmaxf(m0,m1),fmaxf(m2,m3));
      float s0=0.f,s1=0.f,s2=0.f,s3=0.f;
      #pragma unroll
      for(int j4=0;j4<12;j4++){
        const float4 gv=*(const float4*)&GLb[j4*4];
        s0+=ex2(gv.x-Reg[j4*4+0]-mf); s1+=ex2(gv.y-Reg[j4*4+1]-mf);
        s2+=ex2(gv.z-Reg[j4*4+2]-mf); s3+=ex2(gv.w-Reg[j4*4+3]-mf);
      }
      s0+=ex2(GLb[48]-Reg[48]-mf); s1+=ex2(GLb[49]-Reg[49]-mf);
      smf=-(mf+lg2((s0+s1)+(s2+s3)));
    }
    if(gAct){
      float g0=MNEG,g1=MNEG,g2=MNEG,g3=MNEG;
      #pragma unroll
      for(int r4=0;r4<16;r4++){
        const int ai=(gc*2+(r4>>3))*40+((r4&7)<<2);
        const float4 av=*(const float4*)&AfP[ai];
        g0=fmaxf(g0,av.x-Reg[4*r4+0]); g1=fmaxf(g1,av.y-Reg[4*r4+1]);
        g2=fmaxf(g2,av.z-Reg[4*r4+2]); g3=fmaxf(g3,av.w-Reg[4*r4+3]);
      }
      const float gm=fmaxf(fmaxf(g0,g1),fmaxf(g2,g3));
      float s0=0.f,s1=0.f,s2=0.f,s3=0.f;
      #pragma unroll
      for(int r4=0;r4<16;r4++){
        const int ai=(gc*2+(r4>>3))*40+((r4&7)<<2);
        const float4 av=*(const float4*)&AfP[ai];
        s0+=ex2(av.x-Reg[4*r4+0]-gm); s1+=ex2(av.y-Reg[4*r4+1]-gm);
        s2+=ex2(av.z-Reg[4*r4+2]-gm); s3+=ex2(av.w-Reg[4*r4+3]-gm);
      }
      PM[gc*52+col]=gm;
      PS[gc*52+col]=(s0+s1)+(s2+s3);
    }
    __syncthreads();
    if(fAct){
      Fi=(it==0)?smf:0.5f*(Fi+smf);
      AfP[(t>>5)*40+(t&31)]=al2v+Fi;
    }
    if(gAct){
      const float p0=PM[col],p1=PM[52+col],p2=PM[104+col],p3=PM[156+col];
      const float mm=fmaxf(fmaxf(p0,p1),fmaxf(p2,p3));
      const float ssv=PS[col]*ex2(p0-mm)+PS[52+col]*ex2(p1-mm)
                     +PS[104+col]*ex2(p2-mm)+PS[156+col]*ex2(p3-mm);
      const float smg=-(mm+lg2(ssv));
      Gj=(it==0)?smg:0.5f*(Gj+smg);
      if(gc==0) GLb[col]=BL2f+Gj;
    }
    __syncthreads();
  }
  // S[b,c] = ELN*(sum_i a_i F_i + 0.02*sum_j G_j)
  float cv=isF?(weight[(size_t)b*256+t]*Fi):0.f;  // masked rows: weight=0 and/or Fi=0
  #pragma unroll
  for(int off=1;off<64;off<<=1) cv+=__shfl_xor(cv,off);
  if(isF && l==0) red[w]=cv;
  if(w==6){  // gc==0 wave holds full-column Gj (lanes>=50 hold 0)
    float gv=Gj;
    #pragma unroll
    for(int off=1;off<64;off<<=1) gv+=__shfl_xor(gv,off);
    if(l==0) red[4]=gv;
  }
  __syncthreads();
  if(t==0){
    ws[WS_S+b*NC+c]=ELNf*((red[0]+red[1]+red[2]+red[3])+0.02f*red[4]);
  }
}

// ---------------- k_d: margin loss + mean ----------------
__global__ __launch_bounds__(256) void k_d(const int* __restrict__ grade,
                                           const float* __restrict__ ws,
                                           float* __restrict__ out){
  __shared__ float red[4];
  const int t=threadIdx.x;
  const int g=grade[t];
  const float pa=ws[WS_PA+t];
  const float d0=ws[WS_S+t*NC+0]-pa-ws[WS_QC+0];
  const float d1=ws[WS_S+t*NC+1]-pa-ws[WS_QC+1];
  const float d2=ws[WS_S+t*NC+2]-pa-ws[WS_QC+2];
  const float d3=ws[WS_S+t*NC+3]-pa-ws[WS_QC+3];
  const float d4=ws[WS_S+t*NC+4]-pa-ws[WS_QC+4];
  const float pos=(g==0)?d0:(g==1)?d1:(g==2)?d2:(g==3)?d3:d4;
  float loss=0.f;
  if(g!=0) loss+=fmaxf(0.f,pos-d0+10.f);
  if(g!=1) loss+=fmaxf(0.f,pos-d1+10.f);
  if(g!=2) loss+=fmaxf(0.f,pos-d2+10.f);
  if(g!=3) loss+=fmaxf(0.f,pos-d3+10.f);
  if(g!=4) loss+=fmaxf(0.f,pos-d4+10.f);
  loss*=0.2f;
  #pragma unroll
  for(int off=1;off<64;off<<=1) loss+=__shfl_xor(loss,off);
  if((t&63)==0) red[t>>6]=loss;
  __syncthreads();
  if(t==0) out[0]=(red[0]+red[1]+red[2]+red[3])*(1.f/256.f);
}

extern "C" void kernel_launch(void* const* d_in, const int* in_sizes, int n_in,
                              void* d_out, int out_size, void* d_ws, size_t ws_size,
                              hipStream_t stream){
  (void)in_sizes;(void)n_in;(void)out_size;(void)ws_size;
  const float* anchor=(const float*)d_in[0];
  const float* weight=(const float*)d_in[1];
  const float* t0    =(const float*)d_in[2];
  const int*   lena  =(const int*)d_in[4];
  const int*   grade =(const int*)d_in[5];
  float* ws=(float*)d_ws;
  float* out=(float*)d_out;
  k_pre<<<257,256,0,stream>>>(anchor,weight,t0,lena,ws);
  k_ab <<<261,1024,0,stream>>>(anchor,weight,t0,lena,ws);
  k_c  <<<1280,512,0,stream>>>(anchor,weight,t0,lena,ws);
  k_d  <<<1,256,0,stream>>>(grade,ws,out);
}

// Round 7
// 961.976 us; speedup vs baseline: 1.0883x; 1.0883x over previous
//
#include <hip/hip_runtime.h>
#include <math.h>

// Sinkhorn-divergence margin loss, MI355X.
// Scaled domain: F = f/(eps*ln2), M = C/(eps*ln2); softmin via exp2/log2.
// Ragged prefix mask exploited with wave-uniform skips.
// HARD CONSTRAINT (R2-R6 evidence): allocator budgets 64 VGPR for these kernels;
// keep per-thread live floats <= ~55 or it spills to scratch (64-139MB WRITE_SIZE).
#define NL 256
#define ND 300
#define NC 5
#define NR 50

constexpr float SCf  = 577.07801635558534f;     // 1/(eps*ln2), eps=0.0025
constexpr float ELNf = 0.0017328679513998632f;  // eps*ln2
constexpr float BL2f = -5.6438561897747247f;    // log2(1/50)
constexpr float NEGB = -1.0e9f;
constexpr float MNEG = -3.0e38f;

// workspace layout (floats)
#define WS_XN   0        // 65536
#define WS_AL2  65536    // 65536
#define WS_YN   131072   // 256
#define WS_PA   131328   // 256
#define WS_QC   131584   // 16
#define WS_S    131600   // 1280

__device__ __forceinline__ float ex2(float x){ return __builtin_amdgcn_exp2f(x); }
__device__ __forceinline__ float lg2(float x){ return __builtin_amdgcn_logf(x); } // v_log_f32 = log2

// ---------------- k_pre: norms (scaled) + log2-weights ----------------
__global__ __launch_bounds__(256) void k_pre(const float* __restrict__ anchor,
                                             const float* __restrict__ weight,
                                             const float* __restrict__ t0,
                                             const int* __restrict__ lena,
                                             float* __restrict__ ws){
  const int blk=blockIdx.x, t=threadIdx.x;
  if(blk<256){
    const int len=lena[blk];
    const int lenS=(len+63)&~63;
    const int r=blk*256+t;
    if(t<lenS){
      const float4* row=(const float4*)(anchor+(size_t)r*ND);
      float s=0.f;
      #pragma unroll
      for(int k=0;k<75;k++){ float4 v=row[k];
        s=fmaf(v.x,v.x,fmaf(v.y,v.y,fmaf(v.z,v.z,fmaf(v.w,v.w,s)))); }
      ws[WS_XN+r]=0.5f*SCf*s;
    }
    const float w=weight[r];
    ws[WS_AL2+r]=(w>0.f)?log2f(w):NEGB;
  } else if(t<NC*NR){
    const float4* row=(const float4*)(t0+(size_t)t*ND);
    float s=0.f;
    #pragma unroll
    for(int k=0;k<75;k++){ float4 v=row[k];
      s=fmaf(v.x,v.x,fmaf(v.y,v.y,fmaf(v.z,v.z,fmaf(v.w,v.w,s)))); }
    ws[WS_YN+t]=0.5f*SCf*s;
  }
}

// ---------------- k_ab: blocks 0..4 -> q per c; 5..260 -> p per b ----------------
// p: thread (i=t&255, h=t>>8) owns cols [64h,64h+64): 32 in LDS (pass A), 32 in regs (pass B).
__global__ __launch_bounds__(1024)
void k_ab(const float* __restrict__ anchor,
          const float* __restrict__ weight,
          const float* __restrict__ t0,
          const int* __restrict__ lena,
          float* __restrict__ ws){
  __shared__ __align__(16) float POOL[40544];   // 162176 B <= 160 KiB
  const int blk=blockIdx.x, t=threadIdx.x;
  if(blk>=5){
    float4* ML4=(float4*)POOL;                  // [1024 thr][8 f4], swizzled
    float4* xt4=(float4*)(POOL+32768);          // 1288 f4 x-tile
    float*  xnL=POOL+32768+5152;                // 256
    float*  HpP=xnL+256;                        // 4*68
    float*  PM =HpP+272;                        // 4*260
    float*  PS =PM+1040;                        // 4*260
    float*  red=PS+1040;                        // 16
    const int b=blk-5;
    const int len=lena[b];
    const int lenS=(len+63)&~63;
    const int i=t&255, h=t>>8;
    const float* xb=anchor+(size_t)b*NL*ND;
    if(t<256) xnL[t]=ws[WS_XN+b*256+t];
    const float al2=ws[WS_AL2+b*256+i];
    if(t<256) HpP[(t>>6)*68+(t&63)]=al2;        // P=0 init; rows>=len keep -1e9
    for(int e=t;e<1040;e+=1024){ PM[e]=MNEG; PS[e]=0.f; }
    const bool act=(i<len)&&(h*64<len);
    // staging indices
    const int r0=t/5, d40=t-r0*5;
    const bool st0=(r0<lenS);
    const int e1=t+1024, r1=e1/5, d41=e1-r1*5;
    const bool st1=(e1<1280)&&(r1<lenS);
    const float* g0p=xb+(size_t)r0*ND+d40*4;
    const float* g1p=xb+(size_t)r1*ND+d41*4;
    const int u0=5*r0+2*(r0>>6)+d40;
    const int u1=5*r1+2*(r1>>6)+d41;
    const int cb=322*h;                         // col-chunk base in xt4
    const int xti=5*i+2*(i>>6);                 // own-row base in xt4
    const int ub=t*8;                           // own ML4 region (8 units)
    const int sw=i&7;                           // ML swizzle
    float Mr[32];
    float Pi=0.f;
    // -------- two GEMM passes: pass0 cols [64h,64h+32) -> ML; pass1 [64h+32,64h+64) -> regs
    #pragma unroll 1
    for(int pass=0;pass<2;pass++){
      const int KOFF=(pass==0)?0:32;
      #pragma unroll
      for(int k=0;k<32;k++) Mr[k]=0.f;
      float4 pf0,pf1;
      if(st0) pf0=*(const float4*)(g0p);
      if(st1) pf1=*(const float4*)(g1p);
      #pragma unroll 1
      for(int tile=0;tile<15;tile++){
        __syncthreads();
        if(st0) xt4[u0]=pf0;
        if(st1) xt4[u1]=pf1;
        __syncthreads();
        if(tile<14){
          if(st0) pf0=*(const float4*)(g0p+(tile+1)*20);
          if(st1) pf1=*(const float4*)(g1p+(tile+1)*20);
        }
        if(act){
          #pragma unroll 1
          for(int d4=0;d4<5;d4++){
            const float4 xq=xt4[xti+d4];        // own row from staged tile
            #pragma unroll
            for(int kk=0;kk<32;kk++){
              const float4 yv=xt4[cb+5*(KOFF+kk)+d4];  // wave-uniform broadcast
              Mr[kk]=fmaf(xq.x,yv.x,fmaf(xq.y,yv.y,fmaf(xq.z,yv.z,fmaf(xq.w,yv.w,Mr[kk]))));
            }
          }
        }
      }
      if(act){
        const float xni=xnL[i];
        #pragma unroll
        for(int kk=0;kk<32;kk++) Mr[kk]=xni+xnL[64*h+KOFF+kk]-SCf*Mr[kk];
      }
      if(pass==0){
        #pragma unroll
        for(int q4=0;q4<8;q4++){
          float4 v; v.x=Mr[4*q4+0]; v.y=Mr[4*q4+1]; v.z=Mr[4*q4+2]; v.w=Mr[4*q4+3];
          ML4[ub+(q4^sw)]=v;                    // private region, no barrier needed
        }
      }
    }
    __syncthreads();
    // -------- 51 Jacobi passes --------
    const float* Hh=&HpP[h*68];
    #pragma unroll 1
    for(int it=0; it<51; ++it){
      if(act){
        float m0=MNEG,m1=MNEG,m2=MNEG,m3=MNEG;
        #pragma unroll
        for(int q4=0;q4<8;q4++){                // reg half: cols 64h+32+...
          const float4 hv=*(const float4*)&Hh[32+4*q4];
          m0=fmaxf(m0,hv.x-Mr[4*q4+0]); m1=fmaxf(m1,hv.y-Mr[4*q4+1]);
          m2=fmaxf(m2,hv.z-Mr[4*q4+2]); m3=fmaxf(m3,hv.w-Mr[4*q4+3]);
        }
        #pragma unroll
        for(int q4=0;q4<8;q4++){                // LDS half: cols 64h+...
          const float4 mv=ML4[ub+(q4^sw)];
          const float4 hv=*(const float4*)&Hh[4*q4];
          m0=fmaxf(m0,hv.x-mv.x); m1=fmaxf(m1,hv.y-mv.y);
          m2=fmaxf(m2,hv.z-mv.z); m3=fmaxf(m3,hv.w-mv.w);
        }
        const float m=fmaxf(fmaxf(m0,m1),fmaxf(m2,m3));
        float s0=0.f,s1=0.f,s2=0.f,s3=0.f;
        #pragma unroll
        for(int q4=0;q4<8;q4++){
          const float4 hv=*(const float4*)&Hh[32+4*q4];
          s0+=ex2(hv.x-Mr[4*q4+0]-m); s1+=ex2(hv.y-Mr[4*q4+1]-m);
          s2+=ex2(hv.z-Mr[4*q4+2]-m); s3+=ex2(hv.w-Mr[4*q4+3]-m);
        }
        #pragma unroll
        for(int q4=0;q4<8;q4++){
          const float4 mv=ML4[ub+(q4^sw)];
          const float4 hv=*(const float4*)&Hh[4*q4];
          s0+=ex2(hv.x-mv.x-m); s1+=ex2(hv.y-mv.y-m);
          s2+=ex2(hv.z-mv.z-m); s3+=ex2(hv.w-mv.w-m);
        }
        PM[h*260+i]=m;
        PS[h*260+i]=(s0+s1)+(s2+s3);
      }
      __syncthreads();
      if(t<256 && t<len){                       // combine 4 chunk-partials, update H
        const float p0=PM[t],p1=PM[260+t],p2=PM[520+t],p3=PM[780+t];
        const float mm=fmaxf(fmaxf(p0,p1),fmaxf(p2,p3));
        const float ssv=PS[t]*ex2(p0-mm)+PS[260+t]*ex2(p1-mm)
                       +PS[520+t]*ex2(p2-mm)+PS[780+t]*ex2(p3-mm);
        const float sm=-(mm+lg2(ssv));
        Pi=(it==0)?sm:0.5f*(Pi+sm);
        HpP[(t>>6)*68+(t&63)]=al2+Pi;
      }
      __syncthreads();
    }
    float cv=(t<256 && t<len)?(weight[(size_t)b*256+t]*Pi):0.f;
    #pragma unroll
    for(int off=1;off<64;off<<=1) cv+=__shfl_xor(cv,off);
    if((t&63)==0) red[t>>6]=cv;
    __syncthreads();
    if(t==0){ float ss=0.f;
      #pragma unroll
      for(int k2=0;k2<16;k2++) ss+=red[k2];
      ws[WS_PA+b]=ELNf*ss; }
  } else {
    // -------- q per c (50x50), 2 thr/row: My[25] --------
    float* MyL =POOL;          // 50*52
    float* QL  =POOL+2600;     // 64
    float* redq=POOL+2664;     // 2
    const int c=blk;
    const float* yc=t0+(size_t)c*NR*ND;
    #pragma unroll 1
    for(int rr=0;rr<3;rr++){
      const int o=t+1024*rr;
      if(o<2500){
        const int j=o/50, k=o-j*50;
        const float4* a4=(const float4*)(yc+(size_t)j*ND);
        const float4* b4=(const float4*)(yc+(size_t)k*ND);
        float s=0.f;
        #pragma unroll
        for(int d4=0;d4<75;d4++){ const float4 av=a4[d4],bv=b4[d4];
          s=fmaf(av.x,bv.x,fmaf(av.y,bv.y,fmaf(av.z,bv.z,fmaf(av.w,bv.w,s)))); }
        MyL[j*52+k]=ws[WS_YN+c*50+j]+ws[WS_YN+c*50+k]-SCf*s;
      }
    }
    if(t<64) QL[t]=0.f;
    __syncthreads();
    const int j=t>>1, h2=t&1;
    float My[25]; float Qj=0.f;
    if(t<100){
      #pragma unroll
      for(int m=0;m<25;m++) My[m]=MyL[j*52+2*m+h2];
    }
    #pragma unroll 1
    for(int it=0; it<51; ++it){
      float sm=0.f;
      if(t<100){
        float mx=MNEG;
        #pragma unroll
        for(int m=0;m<25;m++) mx=fmaxf(mx,BL2f+QL[2*m+h2]-My[m]);
        mx=fmaxf(mx,__shfl_xor(mx,1));
        float s=0.f;
        #pragma unroll
        for(int m=0;m<25;m++) s+=ex2(BL2f+QL[2*m+h2]-My[m]-mx);
        s+=__shfl_xor(s,1);
        sm=-(mx+lg2(s));
      }
      __syncthreads();
      if(t<100){ Qj=(it==0)?sm:0.5f*(Qj+sm); if(h2==0) QL[j]=Qj; }
      __syncthreads();
    }
    float cv=(t<100&&h2==0)?Qj:0.f;
    #pragma unroll
    for(int off=1;off<64;off<<=1) cv+=__shfl_xor(cv,off);
    if(t==0)  redq[0]=cv;
    if(t==64) redq[1]=cv;
    __syncthreads();
    if(t==0) ws[WS_QC+c]=ELNf*0.02f*(redq[0]+redq[1]);
  }
}

// ---------------- k_c: f,g per (b,c); 512 thr, merged roles ----------------
// f: thread (i=t>>1,h=t&1) owns row i's 25 cols in regs (Mr), shfl-pair combine.
// g: wave w = row-chunk [32w,32w+32), lane l = col; M^T re-read from swizzled LDS.
// skip: wave w fully idle iff 32w >= len (covers f and g). combine: wave 0 only.
__global__ __launch_bounds__(512)
void k_c(const float* __restrict__ anchor,
         const float* __restrict__ weight,
         const float* __restrict__ t0,
         const int* __restrict__ lena,
         float* __restrict__ ws){
  __shared__ __align__(16) float4 MTg4[3200];  // [col<50][unit<64] swizzled: unit^= (col&7)
  __shared__ __align__(16) float yt[1000];     // y-tile [50][20]
  __shared__ float ynL[52];
  __shared__ __align__(16) float AfP[320];     // al2+F: row r -> (r>>5)*40+(r&31)
  __shared__ float GLb[52];                    // BL2f + G
  __shared__ float PM[416];                    // [8][52]
  __shared__ float PS[416];
  __shared__ float red[9];
  const int blk=blockIdx.x, t=threadIdx.x;
  const int c=blk>>8, b=blk&255;
  const int len=lena[b];
  const int i=t>>1, h=t&1;
  const int w=t>>6, l=t&63;
  const bool rowAct=(i<len);
  const bool wAct=(w*32<len);
  const bool gAct=wAct&&(l<50);
  const float* xb=anchor+(size_t)b*NL*ND;
  const float* yc=t0+(size_t)c*NR*ND;
  if(t<50){ ynL[t]=ws[WS_YN+c*50+t]; GLb[t]=BL2f; }
  if(t<416){ PM[t]=MNEG; PS[t]=0.f; }
  const float al2=ws[WS_AL2+b*256+i];
  if(h==0) AfP[(i>>5)*40+(i&31)]=al2;          // F=0 init; rows>=len hold -1e9
  float Mr[25];
  #pragma unroll
  for(int k=0;k<25;k++) Mr[k]=0.f;
  // staging (reg-prefetch)
  const int sr=(t<250)?(t/5):0, sd=(t<250)?(t-(t/5)*5):0;
  const bool stg=(t<250);
  const float* gsp=yc+(size_t)sr*ND+sd*4;
  float4 pf;
  if(stg) pf=*(const float4*)gsp;
  #pragma unroll 1
  for(int tile=0;tile<15;tile++){
    __syncthreads();
    if(stg) *(float4*)&yt[sr*20+sd*4]=pf;
    __syncthreads();
    if(tile<14 && stg) pf=*(const float4*)(gsp+(tile+1)*20);
    if(rowAct){
      const float4* xrow=(const float4*)(xb+(size_t)i*ND+tile*20);
      const float4 xq0=xrow[0],xq1=xrow[1],xq2=xrow[2],xq3=xrow[3],xq4=xrow[4];
      #pragma unroll
      for(int k=0;k<25;k++){
        const int j=2*k+h;
        const float4 y0=*(const float4*)&yt[j*20+0];
        const float4 y1=*(const float4*)&yt[j*20+4];
        const float4 y2=*(const float4*)&yt[j*20+8];
        const float4 y3=*(const float4*)&yt[j*20+12];
        const float4 y4=*(const float4*)&yt[j*20+16];
        float acc=Mr[k];
        acc=fmaf(xq0.x,y0.x,fmaf(xq0.y,y0.y,fmaf(xq0.z,y0.z,fmaf(xq0.w,y0.w,acc))));
        acc=fmaf(xq1.x,y1.x,fmaf(xq1.y,y1.y,fmaf(xq1.z,y1.z,fmaf(xq1.w,y1.w,acc))));
        acc=fmaf(xq2.x,y2.x,fmaf(xq2.y,y2.y,fmaf(xq2.z,y2.z,fmaf(xq2.w,y2.w,acc))));
        acc=fmaf(xq3.x,y3.x,fmaf(xq3.y,y3.y,fmaf(xq3.z,y3.z,fmaf(xq3.w,y3.w,acc))));
        acc=fmaf(xq4.x,y4.x,fmaf(xq4.y,y4.y,fmaf(xq4.z,y4.z,fmaf(xq4.w,y4.w,acc))));
        Mr[k]=acc;
      }
    }
  }
  if(rowAct){
    const float xni=ws[WS_XN+b*256+i];
    #pragma unroll
    for(int k=0;k<25;k++) Mr[k]=xni+ynL[2*k+h]-SCf*Mr[k];
  }
  { // transpose into MTg4 (rows>=len write 0: finite, masked via AfP=-1e9)
    const int cc2=i&3;
    #pragma unroll
    for(int k=0;k<25;k++){
      const int j=2*k+h;
      ((float*)&MTg4[j*64+((i>>2)^(j&7))])[cc2]=Mr[k];
    }
  }
  __syncthreads();
  float Fi=0.f, Gj=0.f;
  const int swl=l&7;
  #pragma unroll 1
  for(int it=0; it<51; ++it){
    float smf=0.f;
    if(wAct){
      // ---- f: row i over 25 cols (regs + GLb broadcasts) ----
      float mf=MNEG;
      #pragma unroll
      for(int k=0;k<25;k++) mf=fmaxf(mf,GLb[2*k+h]-Mr[k]);
      mf=fmaxf(mf,__shfl_xor(mf,1));
      float f0=0.f,f1=0.f;
      #pragma unroll
      for(int k=0;k<25;k++){ float e=ex2(GLb[2*k+h]-Mr[k]-mf); if(k&1) f1+=e; else f0+=e; }
      float fs=f0+f1;
      fs+=__shfl_xor(fs,1);
      smf=-(mf+lg2(fs));
      // ---- g: col l, rows [32w,32w+32) via swizzled M^T re-read ----
      if(gAct){
        float g0=MNEG,g1=MNEG,g2=MNEG,g3=MNEG;
        #pragma unroll
        for(int r4=0;r4<8;r4++){
          const float4 mv=MTg4[l*64+((w*8+r4)^swl)];
          const float4 av=*(const float4*)&AfP[w*40+4*r4];
          g0=fmaxf(g0,av.x-mv.x); g1=fmaxf(g1,av.y-mv.y);
          g2=fmaxf(g2,av.z-mv.z); g3=fmaxf(g3,av.w-mv.w);
        }
        const float gm=fmaxf(fmaxf(g0,g1),fmaxf(g2,g3));
        float s0=0.f,s1=0.f,s2=0.f,s3=0.f;
        #pragma unroll
        for(int r4=0;r4<8;r4++){
          const float4 mv=MTg4[l*64+((w*8+r4)^swl)];
          const float4 av=*(const float4*)&AfP[w*40+4*r4];
          s0+=ex2(av.x-mv.x-gm); s1+=ex2(av.y-mv.y-gm);
          s2+=ex2(av.z-mv.z-gm); s3+=ex2(av.w-mv.w-gm);
        }
        PM[w*52+l]=gm;
        PS[w*52+l]=(s0+s1)+(s2+s3);
      }
    }
    __syncthreads();
    if(wAct){
      Fi=(it==0)?smf:0.5f*(Fi+smf);
      if(h==0 && i<len) AfP[(i>>5)*40+(i&31)]=al2+Fi;
    }
    if(w==0 && l<50){                           // combine 8 chunk-partials (wave 0 only)
      float mm=MNEG;
      float pmv[8];
      #pragma unroll
      for(int q2=0;q2<8;q2++){ pmv[q2]=PM[q2*52+l]; mm=fmaxf(mm,pmv[q2]); }
      float ssv=0.f;
      #pragma unroll
      for(int q2=0;q2<8;q2++) ssv+=PS[q2*52+l]*ex2(pmv[q2]-mm);
      const float smg=-(mm+lg2(ssv));
      Gj=(it==0)?smg:0.5f*(Gj+smg);
      GLb[l]=BL2f+Gj;
    }
    __syncthreads();
  }
  // S[b,c] = ELN*(sum_i a_i F_i + 0.02*sum_j G_j)
  float cv=(h==0 && i<len)?(weight[(size_t)b*256+i]*Fi):0.f;
  #pragma unroll
  for(int off=1;off<64;off<<=1) cv+=__shfl_xor(cv,off);
  if(l==0) red[w]=cv;
  if(w==0){
    float gv=(l<50)?Gj:0.f;
    #pragma unroll
    for(int off=1;off<64;off<<=1) gv+=__shfl_xor(gv,off);
    if(l==0) red[8]=gv;
  }
  __syncthreads();
  if(t==0){
    float sa=red[0]+red[1]+red[2]+red[3]+red[4]+red[5]+red[6]+red[7];
    ws[WS_S+b*NC+c]=ELNf*(sa+0.02f*red[8]);
  }
}

// ---------------- k_d: margin loss + mean ----------------
__global__ __launch_bounds__(256) void k_d(const int* __restrict__ grade,
                                           const float* __restrict__ ws,
                                           float* __restrict__ out){
  __shared__ float red[4];
  const int t=threadIdx.x;
  const int g=grade[t];
  const float pa=ws[WS_PA+t];
  const float d0=ws[WS_S+t*NC+0]-pa-ws[WS_QC+0];
  const float d1=ws[WS_S+t*NC+1]-pa-ws[WS_QC+1];
  const float d2=ws[WS_S+t*NC+2]-pa-ws[WS_QC+2];
  const float d3=ws[WS_S+t*NC+3]-pa-ws[WS_QC+3];
  const float d4=ws[WS_S+t*NC+4]-pa-ws[WS_QC+4];
  const float pos=(g==0)?d0:(g==1)?d1:(g==2)?d2:(g==3)?d3:d4;
  float loss=0.f;
  if(g!=0) loss+=fmaxf(0.f,pos-d0+10.f);
  if(g!=1) loss+=fmaxf(0.f,pos-d1+10.f);
  if(g!=2) loss+=fmaxf(0.f,pos-d2+10.f);
  if(g!=3) loss+=fmaxf(0.f,pos-d3+10.f);
  if(g!=4) loss+=fmaxf(0.f,pos-d4+10.f);
  loss*=0.2f;
  #pragma unroll
  for(int off=1;off<64;off<<=1) loss+=__shfl_xor(loss,off);
  if((t&63)==0) red[t>>6]=loss;
  __syncthreads();
  if(t==0) out[0]=(red[0]+red[1]+red[2]+red[3])*(1.f/256.f);
}

extern "C" void kernel_launch(void* const* d_in, const int* in_sizes, int n_in,
                              void* d_out, int out_size, void* d_ws, size_t ws_size,
                              hipStream_t stream){
  (void)in_sizes;(void)n_in;(void)out_size;(void)ws_size;
  const float* anchor=(const float*)d_in[0];
  const float* weight=(const float*)d_in[1];
  const float* t0    =(const float*)d_in[2];
  const int*   lena  =(const int*)d_in[4];
  const int*   grade =(const int*)d_in[5];
  float* ws=(float*)d_ws;
  float* out=(float*)d_out;
  k_pre<<<257,256,0,stream>>>(anchor,weight,t0,lena,ws);
  k_ab <<<261,1024,0,stream>>>(anchor,weight,t0,lena,ws);
  k_c  <<<1280,512,0,stream>>>(anchor,weight,t0,lena,ws);
  k_d  <<<1,256,0,stream>>>(grade,ws,out);
}